// Round 4
// baseline (214.440 us; speedup 1.0000x reference)
//
#include <hip/hip_runtime.h>
#include <hip/hip_bf16.h>

typedef __bf16  bf16x8  __attribute__((ext_vector_type(8)));
typedef float   floatx4 __attribute__((ext_vector_type(4)));

#define ROWLEN      4096                  // floats per sample row (2048 sites x 2 phys)
#define B_SAMPLES   8192

typedef const __attribute__((address_space(1))) void* gas1_t;
typedef __attribute__((address_space(3))) void*       las3_t;

__device__ __forceinline__ void stage16(const float* g, float* l) {
    // global -> LDS direct, 16 B per lane; LDS dest = uniform base + lane*16
    __builtin_amdgcn_global_load_lds((gas1_t)g, (las3_t)l, 16, 0, 0);
}

// ws layout: [0, 524288) bf16 weight fragments (MFMA B-operand order).
// Fragment layout (bf16x8 per lane, MFMA 16x16x32 B-operand order):
//   frag g = ((h*64 + t)*4 + nt)*64 + lane ; element j (0..7)
//   holds W_h[kk = t*32 + (lane>>4)*8 + j][n = nt*16 + (lane&15)]
// K padded to 2048 per half: h=0 zero-weights kk<2, h=1 zero-weights site 2047.

// 128 blocks x 256 threads: one thread per fragment (8 bf16 = 16 B store).
__global__ __launch_bounds__(256) void repack_kernel(
    const float* __restrict__ left, const float* __restrict__ right,
    __bf16* __restrict__ wfrag)
{
    __shared__ float norms[2];
    const int tid  = threadIdx.x;
    const int wv   = tid >> 6;
    const int ln   = tid & 63;

    if (wv < 2) {
        const float* W = (wv == 0) ? left : right;
        float a = W[384 + ln], b = W[384 + 64 + ln];
        float s = a * a + b * b;
        s += __shfl_xor(s, 1);  s += __shfl_xor(s, 2);  s += __shfl_xor(s, 4);
        s += __shfl_xor(s, 8);  s += __shfl_xor(s, 16); s += __shfl_xor(s, 32);
        if (ln == 0) norms[wv] = 1.0f / sqrtf(s);
    }
    __syncthreads();
    const float invL = norms[0];
    const float invR = norms[1];

    const int g    = (int)(blockIdx.x * 256) + tid;   // fragment index [0,32768)
    const int lane = g & 63;
    const int nt   = (g >> 6) & 3;
    const int t    = (g >> 8) & 63;
    const int h    = (g >> 14) & 1;
    const int kk0  = t * 32 + (lane >> 4) * 8;
    const int n    = nt * 16 + (lane & 15);
    const int a    = n >> 3, bb = n & 7;
    const float* W = (h == 0) ? left : right;

    bf16x8 frag;
#pragma unroll
    for (int si = 0; si < 4; ++si) {
        const int kk = kk0 + si * 2;
        int s;  bool valid;
        if (h == 0) { s = (kk >> 1) - 1; valid = (kk >= 2); }
        else        { s = (kk >> 1);     valid = (s < 1023); }
        float w0 = 0.f, w1 = 0.f;
        if (valid) {
            const float* wp = W + ((s * 8 + a) * 8 + bb) * 2;
            w0 = wp[0]; w1 = wp[1];
            if (s == 3) { const float sc = (h == 0) ? invL : invR; w0 *= sc; w1 *= sc; }
        }
        frag[si * 2]     = (__bf16)w0;
        frag[si * 2 + 1] = (__bf16)w1;
    }
    ((bf16x8*)wfrag)[g] = frag;
}

// 256 blocks x 512 threads, 1 block/CU (128 KB LDS). LDS-staged linear x-stream:
//  - 8 chunks of 512 floats per row; per chunk each wave stages 4 rows with
//    global_load_lds width=16 -> every vmem instr is 1 KB CONTIGUOUS in one row
//    (vs 16 half-used lines/instr in the register-direct version).
//  - granule XOR swizzle (pos = g ^ (row&7)) applied by permuting the per-lane
//    GLOBAL source address (gl_lds dest must stay linear); ds_read_b128 at the
//    same XOR -> uniform 8 lanes/bank-quad (conflict-free throughput).
//  - waves: all stage every chunk; waves with (wid&1)==chunk.h compute 4 K-tiles
//    each (v = wid>>1 picks the t-slice). 2-phase: stage(next) || compute(cur),
//    one __syncthreads per chunk.
__global__ __launch_bounds__(512, 2) void mps_main_kernel(
    const float* __restrict__ x, const __bf16* __restrict__ wfrag,
    const float* __restrict__ left_b, const float* __restrict__ right_b,
    float* __restrict__ out)
{
    __shared__ float smem[32768];        // 2 x 64 KB staging; reused as epilogue buf
    const int tid  = threadIdx.x;
    const int wid  = tid >> 6;           // 8 waves
    const int lane = tid & 63;
    const int hw   = wid & 1;            // this wave's compute half
    const int v    = wid >> 1;           // t-slice 0..3
    const int mcol = lane & 15;
    const int q    = lane >> 4;
    const int p    = lane & 7;           // = mcol&7 = (16+mcol)&7, read-side XOR
    const int blk  = blockIdx.x;

    const float* xblk = x + (size_t)blk * 32 * ROWLEN;

    // prologue: stage chunk 0 (h=0,c=0) into buf0
#pragma unroll
    for (int i = 0; i < 4; ++i) {
        const int r = 4 * wid + i;
        const float* gp = xblk + (size_t)r * ROWLEN + ((lane ^ (r & 7)) * 4);
        stage16(gp,       &smem[r * 512]);
        stage16(gp + 256, &smem[r * 512 + 256]);
    }
    __syncthreads();

    floatx4 accA0 = {0.f,0.f,0.f,0.f}, accA1 = {0.f,0.f,0.f,0.f};
    floatx4 accA2 = {0.f,0.f,0.f,0.f}, accA3 = {0.f,0.f,0.f,0.f};
    floatx4 accB0 = {0.f,0.f,0.f,0.f}, accB1 = {0.f,0.f,0.f,0.f};
    floatx4 accB2 = {0.f,0.f,0.f,0.f}, accB3 = {0.f,0.f,0.f,0.f};

#pragma unroll
    for (int ch = 0; ch < 8; ++ch) {
        const int cbuf = (ch & 1) * 16384;
        if (ch < 7) {                       // issue next chunk's staging first
            const int cn     = ch + 1;
            const int coloff = (cn & 1) * 2048 + (cn >> 1) * 512;
            const int nbuf   = (cn & 1) * 16384;
#pragma unroll
            for (int i = 0; i < 4; ++i) {
                const int r = 4 * wid + i;
                const float* gp = xblk + (size_t)r * ROWLEN + coloff
                                + ((lane ^ (r & 7)) * 4);
                stage16(gp,       &smem[nbuf + r * 512]);
                stage16(gp + 256, &smem[nbuf + r * 512 + 256]);
            }
        }
        if ((ch & 1) == hw) {               // this wave computes this chunk
            const int cc = ch >> 1;
            const float* sA = &smem[cbuf + mcol * 512];
            const float* sB = &smem[cbuf + (16 + mcol) * 512];
            const bf16x8* bp0 = (const bf16x8*)wfrag
                + ((size_t)((hw * 64 + cc * 16 + 4 * v) * 4)) * 64 + lane;
#pragma unroll
            for (int ti = 0; ti < 4; ++ti) {
                const int g0 = (4 * v + ti) * 8 + 2 * q;
                const floatx4 a0 = *(const floatx4*)&sA[((g0    ) ^ p) * 4];
                const floatx4 a1 = *(const floatx4*)&sA[((g0 + 1) ^ p) * 4];
                const floatx4 b0 = *(const floatx4*)&sB[((g0    ) ^ p) * 4];
                const floatx4 b1 = *(const floatx4*)&sB[((g0 + 1) ^ p) * 4];
                bf16x8 af0, af1;
                af0[0] = (__bf16)a0[0]; af0[1] = (__bf16)a0[1];
                af0[2] = (__bf16)a0[2]; af0[3] = (__bf16)a0[3];
                af0[4] = (__bf16)a1[0]; af0[5] = (__bf16)a1[1];
                af0[6] = (__bf16)a1[2]; af0[7] = (__bf16)a1[3];
                af1[0] = (__bf16)b0[0]; af1[1] = (__bf16)b0[1];
                af1[2] = (__bf16)b0[2]; af1[3] = (__bf16)b0[3];
                af1[4] = (__bf16)b1[0]; af1[5] = (__bf16)b1[1];
                af1[6] = (__bf16)b1[2]; af1[7] = (__bf16)b1[3];
                const bf16x8* bp = bp0 + (size_t)ti * 256;
                const bf16x8 w0 = bp[0], w1 = bp[64], w2 = bp[128], w3 = bp[192];
                accA0 = __builtin_amdgcn_mfma_f32_16x16x32_bf16(af0, w0, accA0, 0, 0, 0);
                accB0 = __builtin_amdgcn_mfma_f32_16x16x32_bf16(af1, w0, accB0, 0, 0, 0);
                accA1 = __builtin_amdgcn_mfma_f32_16x16x32_bf16(af0, w1, accA1, 0, 0, 0);
                accB1 = __builtin_amdgcn_mfma_f32_16x16x32_bf16(af1, w1, accB1, 0, 0, 0);
                accA2 = __builtin_amdgcn_mfma_f32_16x16x32_bf16(af0, w2, accA2, 0, 0, 0);
                accB2 = __builtin_amdgcn_mfma_f32_16x16x32_bf16(af1, w2, accB2, 0, 0, 0);
                accA3 = __builtin_amdgcn_mfma_f32_16x16x32_bf16(af0, w3, accA3, 0, 0, 0);
                accB3 = __builtin_amdgcn_mfma_f32_16x16x32_bf16(af1, w3, accB3, 0, 0, 0);
            }
        }
        __syncthreads();   // vmcnt(0)+lgkmcnt(0): staging landed, reads done
    }

    // epilogue: overlay smem as float[2][4][32][65] wave-partials
    {
        const int base = (hw * 4 + v) * 32;
#pragma unroll
        for (int i = 0; i < 4; ++i) {
            const int r0 = q * 4 + i;
            smem[(base + r0) * 65 +  0 + mcol] = accA0[i];
            smem[(base + r0) * 65 + 16 + mcol] = accA1[i];
            smem[(base + r0) * 65 + 32 + mcol] = accA2[i];
            smem[(base + r0) * 65 + 48 + mcol] = accA3[i];
            smem[(base + 16 + r0) * 65 +  0 + mcol] = accB0[i];
            smem[(base + 16 + r0) * 65 + 16 + mcol] = accB1[i];
            smem[(base + 16 + r0) * 65 + 32 + mcol] = accB2[i];
            smem[(base + 16 + r0) * 65 + 48 + mcol] = accB3[i];
        }
    }
    __syncthreads();

    if (tid < 256) {
        const int mm = tid >> 3;          // sample within block (0..31)
        const int b  = tid & 7;           // bond index b
        const size_t k = (size_t)blk * 32 + mm;
        const float* xr = x + k * ROWLEN;
        const float x0 = xr[0],    x1 = xr[1];        // x[k, 0, :]
        const float y0 = xr[4094], y1 = xr[4095];     // x[k, 2047, :]
        const float lbn = 1.0f / sqrtf(left_b[4]*left_b[4] + left_b[5]*left_b[5]);
        const float rbn = 1.0f / sqrtf(right_b[4]*right_b[4] + right_b[5]*right_b[5]);
        float l = 0.f, r = 0.f;
#pragma unroll
        for (int a = 0; a < 8; ++a) {
            float lv = left_b[a*2]  * x0 + left_b[a*2+1]  * x1;
            float rv = right_b[a*2] * y0 + right_b[a*2+1] * y1;
            if (a == 2) { lv *= lbn; rv *= rbn; }
            const int n = a * 8 + b;
            const float ls = smem[((0*4+0)*32 + mm)*65 + n] + smem[((0*4+1)*32 + mm)*65 + n]
                           + smem[((0*4+2)*32 + mm)*65 + n] + smem[((0*4+3)*32 + mm)*65 + n];
            const float rs = smem[((1*4+0)*32 + mm)*65 + n] + smem[((1*4+1)*32 + mm)*65 + n]
                           + smem[((1*4+2)*32 + mm)*65 + n] + smem[((1*4+3)*32 + mm)*65 + n];
            l += lv * ls;
            r += rv * rs;
        }
        float vv = l * r;
        vv += __shfl_xor(vv, 1);
        vv += __shfl_xor(vv, 2);
        vv += __shfl_xor(vv, 4);
        if (b == 0) out[k] = vv;
    }
}

extern "C" void kernel_launch(void* const* d_in, const int* in_sizes, int n_in,
                              void* d_out, int out_size, void* d_ws, size_t ws_size,
                              hipStream_t stream)
{
    const float* x       = (const float*)d_in[0];
    const float* left_b  = (const float*)d_in[1];
    const float* left    = (const float*)d_in[2];
    const float* right   = (const float*)d_in[3];
    const float* right_b = (const float*)d_in[4];

    __bf16* wfrag = (__bf16*)d_ws;
    float*  out   = (float*)d_out;

    hipLaunchKernelGGL(repack_kernel, dim3(128), dim3(256), 0, stream,
                       left, right, wfrag);
    hipLaunchKernelGGL(mps_main_kernel, dim3(B_SAMPLES / 32), dim3(512), 0, stream,
                       x, wfrag, left_b, right_b, out);
}

// Round 5
// 206.954 us; speedup vs baseline: 1.0362x; 1.0362x over previous
//
#include <hip/hip_runtime.h>
#include <hip/hip_bf16.h>

typedef __bf16  bf16x8  __attribute__((ext_vector_type(8)));
typedef float   floatx4 __attribute__((ext_vector_type(4)));

#define ROWLEN      4096                  // floats per sample row (2048 sites x 2 phys)
#define B_SAMPLES   8192

typedef const __attribute__((address_space(1))) void* gas1_t;
typedef __attribute__((address_space(3))) void*       las3_t;

__device__ __forceinline__ void stage16(const float* g, float* l) {
    // global -> LDS direct, 16 B per lane; LDS dest = uniform base + lane*16
    __builtin_amdgcn_global_load_lds((gas1_t)g, (las3_t)l, 16, 0, 0);
}

// ws layout: [0, 524288) bf16 weight fragments (MFMA B-operand order).
// Fragment layout (bf16x8 per lane, MFMA 16x16x32 B-operand order):
//   frag g = ((h*64 + t)*4 + nt)*64 + lane ; element j (0..7)
//   holds W_h[kk = t*32 + (lane>>4)*8 + j][n = nt*16 + (lane&15)]
// K padded to 2048 per half: h=0 zero-weights kk<2, h=1 zero-weights site 2047.

// 128 blocks x 256 threads: one thread per fragment (8 bf16 = 16 B store).
__global__ __launch_bounds__(256) void repack_kernel(
    const float* __restrict__ left, const float* __restrict__ right,
    __bf16* __restrict__ wfrag)
{
    __shared__ float norms[2];
    const int tid  = threadIdx.x;
    const int wv   = tid >> 6;
    const int ln   = tid & 63;

    if (wv < 2) {
        const float* W = (wv == 0) ? left : right;
        float a = W[384 + ln], b = W[384 + 64 + ln];
        float s = a * a + b * b;
        s += __shfl_xor(s, 1);  s += __shfl_xor(s, 2);  s += __shfl_xor(s, 4);
        s += __shfl_xor(s, 8);  s += __shfl_xor(s, 16); s += __shfl_xor(s, 32);
        if (ln == 0) norms[wv] = 1.0f / sqrtf(s);
    }
    __syncthreads();
    const float invL = norms[0];
    const float invR = norms[1];

    const int g    = (int)(blockIdx.x * 256) + tid;   // fragment index [0,32768)
    const int lane = g & 63;
    const int nt   = (g >> 6) & 3;
    const int t    = (g >> 8) & 63;
    const int h    = (g >> 14) & 1;
    const int kk0  = t * 32 + (lane >> 4) * 8;
    const int n    = nt * 16 + (lane & 15);
    const int a    = n >> 3, bb = n & 7;
    const float* W = (h == 0) ? left : right;

    bf16x8 frag;
#pragma unroll
    for (int si = 0; si < 4; ++si) {
        const int kk = kk0 + si * 2;
        int s;  bool valid;
        if (h == 0) { s = (kk >> 1) - 1; valid = (kk >= 2); }
        else        { s = (kk >> 1);     valid = (s < 1023); }
        float w0 = 0.f, w1 = 0.f;
        if (valid) {
            const float* wp = W + ((s * 8 + a) * 8 + bb) * 2;
            w0 = wp[0]; w1 = wp[1];
            if (s == 3) { const float sc = (h == 0) ? invL : invR; w0 *= sc; w1 *= sc; }
        }
        frag[si * 2]     = (__bf16)w0;
        frag[si * 2 + 1] = (__bf16)w1;
    }
    ((bf16x8*)wfrag)[g] = frag;
}

// 256 blocks x 512 threads, 1 block/CU (128 KB LDS). Counted-vmcnt pipeline:
// per chunk: [wfrag loads FIRST][next-chunk stage16s][s_waitcnt vmcnt(8):
// the 8 next-chunk stages stay IN FLIGHT across the barrier; in-order vmem
// retire => waiting the wfrag loads implies current chunk's stage landed]
// [s_barrier][compute: ALL 8 waves][s_barrier]. No vmcnt(0) in the loop.
// Wave w: sample-half AB = w&1 (rows 16*AB..+16), t-slice v = w>>1;
// accumulates acc[h][nt] across chunks (h = ch&1, c = ch>>1).
__global__ __launch_bounds__(512, 2) void mps_main_kernel(
    const float* __restrict__ x, const __bf16* __restrict__ wfrag,
    const float* __restrict__ left_b, const float* __restrict__ right_b,
    float* __restrict__ out)
{
    __shared__ float smem[32768];        // 2 x 64 KB staging; reused as epilogue buf
    const int tid  = threadIdx.x;
    const int wid  = tid >> 6;           // 8 waves
    const int lane = tid & 63;
    const int AB   = wid & 1;            // sample half (rows 16*AB .. +16)
    const int v    = wid >> 1;           // t-slice 0..3 within each (h,c)
    const int mcol = lane & 15;
    const int q    = lane >> 4;
    const int p    = lane & 7;           // read-side granule XOR (= row&7)
    const int blk  = blockIdx.x;

    const float* xblk = x + (size_t)blk * 32 * ROWLEN;

    // prologue: stage chunk 0 (h=0,c=0) into buf0 (granule-swizzled source)
#pragma unroll
    for (int i = 0; i < 4; ++i) {
        const int r = 4 * wid + i;
        const float* gp = xblk + (size_t)r * ROWLEN + ((lane ^ (r & 7)) * 4);
        stage16(gp,       &smem[r * 512]);
        stage16(gp + 256, &smem[r * 512 + 256]);
    }

    floatx4 accL[4] = {{0.f,0.f,0.f,0.f},{0.f,0.f,0.f,0.f},
                       {0.f,0.f,0.f,0.f},{0.f,0.f,0.f,0.f}};
    floatx4 accR[4] = {{0.f,0.f,0.f,0.f},{0.f,0.f,0.f,0.f},
                       {0.f,0.f,0.f,0.f},{0.f,0.f,0.f,0.f}};

#pragma unroll
    for (int ch = 0; ch < 8; ++ch) {
        const int h    = ch & 1;
        const int c    = ch >> 1;
        const int cbuf = (ch & 1) * 16384;

        // --- W(ch): wfrag loads FIRST (older than next-chunk stages) ---
        bf16x8 w[4][4];
        const bf16x8* bp0 = (const bf16x8*)wfrag
            + ((size_t)((h * 64 + c * 16 + 4 * v) * 4)) * 64 + lane;
#pragma unroll
        for (int ti = 0; ti < 4; ++ti)
#pragma unroll
            for (int nt = 0; nt < 4; ++nt)
                w[ti][nt] = bp0[(size_t)ti * 256 + nt * 64];
        __builtin_amdgcn_sched_barrier(0);

        // --- S(ch+1): stage next chunk (8 x global_load_lds per wave) ---
        if (ch < 7) {
            const int cn     = ch + 1;
            const int coloff = (cn & 1) * 2048 + (cn >> 1) * 512;
            const int nbuf   = (cn & 1) * 16384;
#pragma unroll
            for (int i = 0; i < 4; ++i) {
                const int r = 4 * wid + i;
                const float* gp = xblk + (size_t)r * ROWLEN + coloff
                                + ((lane ^ (r & 7)) * 4);
                stage16(gp,       &smem[nbuf + r * 512]);
                stage16(gp + 256, &smem[nbuf + r * 512 + 256]);
            }
            __builtin_amdgcn_sched_barrier(0);
            asm volatile("s_waitcnt vmcnt(8)" ::: "memory");
        } else {
            __builtin_amdgcn_sched_barrier(0);
            asm volatile("s_waitcnt vmcnt(0)" ::: "memory");
        }
        __builtin_amdgcn_s_barrier();
        __builtin_amdgcn_sched_barrier(0);

        // --- compute(ch): all waves; 4 t-tiles x 4 nt = 16 MFMAs ---
        {
            floatx4* acc = (h == 0) ? accL : accR;
            const float* sA = &smem[cbuf + (16 * AB + mcol) * 512];
#pragma unroll
            for (int ti = 0; ti < 4; ++ti) {
                const int g0 = (4 * v + ti) * 8 + 2 * q;
                const floatx4 a0 = *(const floatx4*)&sA[((g0    ) ^ p) * 4];
                const floatx4 a1 = *(const floatx4*)&sA[((g0 + 1) ^ p) * 4];
                bf16x8 af;
                af[0] = (__bf16)a0[0]; af[1] = (__bf16)a0[1];
                af[2] = (__bf16)a0[2]; af[3] = (__bf16)a0[3];
                af[4] = (__bf16)a1[0]; af[5] = (__bf16)a1[1];
                af[6] = (__bf16)a1[2]; af[7] = (__bf16)a1[3];
                acc[0] = __builtin_amdgcn_mfma_f32_16x16x32_bf16(af, w[ti][0], acc[0], 0, 0, 0);
                acc[1] = __builtin_amdgcn_mfma_f32_16x16x32_bf16(af, w[ti][1], acc[1], 0, 0, 0);
                acc[2] = __builtin_amdgcn_mfma_f32_16x16x32_bf16(af, w[ti][2], acc[2], 0, 0, 0);
                acc[3] = __builtin_amdgcn_mfma_f32_16x16x32_bf16(af, w[ti][3], acc[3], 0, 0, 0);
            }
        }
        __builtin_amdgcn_sched_barrier(0);
        __builtin_amdgcn_s_barrier();
    }

    // epilogue: overlay smem as float[2][4][32][65] (h, v, sample, n) partials
#pragma unroll
    for (int i = 0; i < 4; ++i) {
        const int row = 16 * AB + q * 4 + i;
        smem[((0 * 4 + v) * 32 + row) * 65 +  0 + mcol] = accL[0][i];
        smem[((0 * 4 + v) * 32 + row) * 65 + 16 + mcol] = accL[1][i];
        smem[((0 * 4 + v) * 32 + row) * 65 + 32 + mcol] = accL[2][i];
        smem[((0 * 4 + v) * 32 + row) * 65 + 48 + mcol] = accL[3][i];
        smem[((1 * 4 + v) * 32 + row) * 65 +  0 + mcol] = accR[0][i];
        smem[((1 * 4 + v) * 32 + row) * 65 + 16 + mcol] = accR[1][i];
        smem[((1 * 4 + v) * 32 + row) * 65 + 32 + mcol] = accR[2][i];
        smem[((1 * 4 + v) * 32 + row) * 65 + 48 + mcol] = accR[3][i];
    }
    __syncthreads();

    if (tid < 256) {
        const int mm = tid >> 3;          // sample within block (0..31)
        const int b  = tid & 7;           // bond index b
        const size_t k = (size_t)blk * 32 + mm;
        const float* xr = x + k * ROWLEN;
        const float x0 = xr[0],    x1 = xr[1];        // x[k, 0, :]
        const float y0 = xr[4094], y1 = xr[4095];     // x[k, 2047, :]
        const float lbn = 1.0f / sqrtf(left_b[4]*left_b[4] + left_b[5]*left_b[5]);
        const float rbn = 1.0f / sqrtf(right_b[4]*right_b[4] + right_b[5]*right_b[5]);
        float l = 0.f, r = 0.f;
#pragma unroll
        for (int a = 0; a < 8; ++a) {
            float lv = left_b[a*2]  * x0 + left_b[a*2+1]  * x1;
            float rv = right_b[a*2] * y0 + right_b[a*2+1] * y1;
            if (a == 2) { lv *= lbn; rv *= rbn; }
            const int n = a * 8 + b;
            const float ls = smem[((0*4+0)*32 + mm)*65 + n] + smem[((0*4+1)*32 + mm)*65 + n]
                           + smem[((0*4+2)*32 + mm)*65 + n] + smem[((0*4+3)*32 + mm)*65 + n];
            const float rs = smem[((1*4+0)*32 + mm)*65 + n] + smem[((1*4+1)*32 + mm)*65 + n]
                           + smem[((1*4+2)*32 + mm)*65 + n] + smem[((1*4+3)*32 + mm)*65 + n];
            l += lv * ls;
            r += rv * rs;
        }
        float vv = l * r;
        vv += __shfl_xor(vv, 1);
        vv += __shfl_xor(vv, 2);
        vv += __shfl_xor(vv, 4);
        if (b == 0) out[k] = vv;
    }
}

extern "C" void kernel_launch(void* const* d_in, const int* in_sizes, int n_in,
                              void* d_out, int out_size, void* d_ws, size_t ws_size,
                              hipStream_t stream)
{
    const float* x       = (const float*)d_in[0];
    const float* left_b  = (const float*)d_in[1];
    const float* left    = (const float*)d_in[2];
    const float* right   = (const float*)d_in[3];
    const float* right_b = (const float*)d_in[4];

    __bf16* wfrag = (__bf16*)d_ws;
    float*  out   = (float*)d_out;

    hipLaunchKernelGGL(repack_kernel, dim3(128), dim3(256), 0, stream,
                       left, right, wfrag);
    hipLaunchKernelGGL(mps_main_kernel, dim3(B_SAMPLES / 32), dim3(512), 0, stream,
                       x, wfrag, left_b, right_b, out);
}